// Round 9
// baseline (357.197 us; speedup 1.0000x reference)
//
#include <hip/hip_runtime.h>
#include <cmath>

typedef _Float16 half8 __attribute__((ext_vector_type(8)));
typedef _Float16 half4 __attribute__((ext_vector_type(4)));
typedef _Float16 half2v __attribute__((ext_vector_type(2)));
typedef __fp16 fp16x2 __attribute__((ext_vector_type(2)));   // cvt_pkrtz return type
typedef float f32x4 __attribute__((ext_vector_type(4)));
typedef float f32x2 __attribute__((ext_vector_type(2)));

#define B_ 2
#define L_ 2048
#define H_ 8
#define D_ 64
#define S_ 2
#define F_ 5
#define LUTN 2048
#define LSCALE 1448.1547f          // LUTN / sqrt(2)
#define LOG2E 1.44269504f
#define QSC (0.125f * LOG2E)       // folded into Q at preprocess

// ws layout: Q tiles (64x64 f16, swizzled), K tiles (32x64 f16, swizzled),
// VT tiles (superrow-swizzled f16, KEY-PERMUTED for register-resident P),
// then pre-scaled ks_s coords (f32).
#define QOFF 0            // halfs
#define KOFF 2097152      // halfs
#define VOFF 4194304      // halfs
#define SOFFH 6291456     // halfs -> (float*)(wsh + SOFFH)
#define WS_NEED 12615680  // bytes

// main-kernel LDS arena (bytes): SINGLE-buffered K/V (8 groups x 4 KB each) + LUT.
// Single buffer (prefetch was proven null at 2 blocks/CU in R2) frees LDS for
// 16-wave blocks -> 2 blocks/CU x 16 waves = 32 waves/CU (full occupancy).
#define OFF_K 0            // 8 x 4096
#define OFF_V 32768        // 8 x 4096
#define OFF_LUT 65536      // 2049 x 4 (+pad)
#define ARENA_SZ 73744
#define SLOTF (16 * 68 + 16)   // combine slot: O[16][68] f32 + l[16]

#define GLOBAL_LOAD_LDS16(g, l)                                                  \
  __builtin_amdgcn_global_load_lds((const __attribute__((address_space(1))) void*)(g), \
                                   (__attribute__((address_space(3))) void*)(l), 16, 0, 0)

// raw v_sqrt_f32 (1 ULP) — result only feeds a 2048-bin LUT quantizer.
#define FAST_SQRT(x) __builtin_amdgcn_sqrtf(x)

// ---------------- preprocessing: f32 -> f16 swizzled tiles in ws ----------------
// (R8 version, unchanged) grid 512 x 512 thr: (bh,u) per block.
#define VTS 68   // VT row stride in halfs (34 dwords; odd dword stride -> spread)
__global__ __launch_bounds__(512, 8)
void tisa_preproc(const float* __restrict__ qs, const float* __restrict__ ks,
                  const float* __restrict__ vs, const float* __restrict__ ks_s,
                  _Float16* __restrict__ wsh) {
  __shared__ _Float16 VT[64 * VTS];   // [d 64][key 64 (+4 pad)]
  const int t = threadIdx.x;
  const int bid = blockIdx.x;
  const int xcd = bid & 7, slot = bid >> 3;
  const int u = slot & 31;
  const int bh = xcd * 2 + (slot >> 5);
  const size_t base = ((size_t)(bh >> 3) * L_ + (size_t)u * 64) * (H_ * D_) + (size_t)(bh & 7) * D_;

  // ---- Q: 512 chunks of 8 f32 -> 8 f16, swizzled chunk c^(row&7), scaled by QSC ----
  {
    int row = t >> 3, c = t & 7;
    const float* src = qs + base + (size_t)row * 512 + c * 8;
    f32x4 x0 = ((const f32x4*)src)[0], x1 = ((const f32x4*)src)[1];
    half8 hh;
#pragma unroll
    for (int k = 0; k < 4; ++k) { hh[k] = (_Float16)(x0[k] * QSC); hh[k + 4] = (_Float16)(x1[k] * QSC); }
    *(half8*)&wsh[QOFF + ((size_t)bh * 32 + u) * 4096 + row * 64 + (c ^ (row & 7)) * 8] = hh;
  }
  // ---- K: two 32-row tiles, same chunk swizzle ----
  {
    int tile = t >> 8, row = (t >> 3) & 31, c = t & 7;
    const float* src = ks + base + (size_t)(tile * 32 + row) * 512 + c * 8;
    f32x4 x0 = ((const f32x4*)src)[0], x1 = ((const f32x4*)src)[1];
    half8 hh;
#pragma unroll
    for (int k = 0; k < 4; ++k) { hh[k] = (_Float16)x0[k]; hh[k + 4] = (_Float16)x1[k]; }
    *(half8*)&wsh[KOFF + ((size_t)bh * 64 + u * 2 + tile) * 2048 + row * 64 + (c ^ (row & 7)) * 8] = hh;
  }
  // ---- scaled ks_s coords (h==0 blocks only; 64 keys = 128 floats) ----
  if ((bh & 7) == 0 && t < 32) {
    const int b = bh >> 3;
    const float* src = ks_s + ((size_t)b * L_ + u * 64) * 2 + t * 4;
    float* dst = (float*)(wsh + SOFFH) + ((size_t)b * L_ + u * 64) * 2 + t * 4;
    f32x4 x = *(const f32x4*)src;
    x *= LSCALE;
    *(f32x4*)dst = x;
  }
  // ---- V: register transpose -> VT[d][key] (threads 0..255: 2 keys x 8 d) ----
  if (t < 256) {
    int kk = (t & 31) * 2, dg = (t >> 5) * 8;
    const float* s0 = vs + base + (size_t)kk * 512 + dg;
    const float* s1 = s0 + 512;
    f32x4 a0 = ((const f32x4*)s0)[0], a1 = ((const f32x4*)s0)[1];
    f32x4 b0 = ((const f32x4*)s1)[0], b1 = ((const f32x4*)s1)[1];
#pragma unroll
    for (int v = 0; v < 4; ++v) {
      half2v p0 = {(_Float16)a0[v], (_Float16)b0[v]};
      *(half2v*)&VT[(dg + v) * VTS + kk] = p0;
      half2v p1 = {(_Float16)a1[v], (_Float16)b1[v]};
      *(half2v*)&VT[(dg + 4 + v) * VTS + kk] = p1;
    }
  }
  __syncthreads();
  // ---- gather key'-ordered half8 from VT rows (2x contiguous b64), write ws ----
  {
    int tile = t >> 8, s = (t >> 3) & 31, cp2 = t & 7;
    int d = 2 * s + (cp2 >> 2), qp = cp2 & 3;
    half4 lo = *(const half4*)&VT[d * VTS + tile * 32 + qp * 4];        // nf=0
    half4 hi = *(const half4*)&VT[d * VTS + tile * 32 + 16 + qp * 4];   // nf=1
    half8 hh;
#pragma unroll
    for (int j = 0; j < 4; ++j) { hh[j] = lo[j]; hh[j + 4] = hi[j]; }
    *(half8*)&wsh[VOFF + ((size_t)bh * 64 + u * 2 + tile) * 2048 + s * 64 + (cp2 ^ (s & 7)) * 8] = hh;
  }
}

// ---------------- main kernel: 1024 thr = 16 waves = 8 K-groups x 2 q-halves --------
// N_rep=2 (each wave owns two q-slices; kf/vf read ONCE per group). 8 groups x
// 256 keys over 8 iterations, single-buffered staging -> 73.7 KB LDS, 16-wave
// blocks, 2 blocks/CU = 32 waves/CU (was 16: occupancy was the limiter).
__global__ __launch_bounds__(1024, 8)
void tisa_attn_main(const float* __restrict__ qs_s, const float* __restrict__ ap,
                    const float* __restrict__ bp, const float* __restrict__ cp,
                    const _Float16* __restrict__ wsh, float* __restrict__ out) {
  __shared__ __align__(16) char arena[ARENA_SZ];
  float* LUT = (float*)(arena + OFF_LUT);

  const int t = threadIdx.x;
  const int lane = t & 63;
  const int w = t >> 6;       // 0..15
  const int g = w >> 1;       // K-group 0..7 (256 keys each)
  const int qh = w & 1;       // q-half 0..1 (owns q-slices 2qh, 2qh+1)
  const int tg = t & 127;     // index within group (2 waves)
  const int quad = lane >> 4;
  const int l16 = lane & 15;

  // XCD swizzle: each XCD gets a contiguous bh-pair -> K/V stays L2-resident.
  const int bid = blockIdx.x;
  const int xcd = bid & 7, slot = bid >> 3;
  const int qt = slot & 31;
  const int bh = xcd * 2 + (slot >> 5);
  const int h = bh & 7;
  const int b = bh >> 3;
  const int q0 = qt * 64;

  // ---- LUT (nearest-neighbor, midpoint-sampled): ((bias-8)*log2e) at d=(i+0.5)/LSCALE ----
  {
    float af[F_], nb[F_], cf[F_];
#pragma unroll
    for (int f = 0; f < F_; ++f) {
      af[f] = ap[h * F_ + f];
      nb[f] = -fabsf(bp[h * F_ + f]);
      cf[f] = cp[h * F_ + f];
    }
    for (int i = t; i <= LUTN; i += 1024) {
      float d = ((float)i + 0.5f) * (1.0f / LSCALE);
      float s = 0.f;
#pragma unroll
      for (int f = 0; f < F_; ++f) {
        float e = d - cf[f];
        s += af[f] * __expf(nb[f] * (e * e));
      }
      LUT[i] = (s - 8.0f) * LOG2E;
    }
  }

  // q coords for this lane's two S^T columns (q = (2qh+s)*16 + l16), pre-scaled
  float qx[2], qy[2];
#pragma unroll
  for (int s = 0; s < 2; ++s) {
    qx[s] = qs_s[((size_t)b * L_ + q0 + (qh * 2 + s) * 16 + l16) * 2 + 0] * LSCALE;
    qy[s] = qs_s[((size_t)b * L_ + q0 + (qh * 2 + s) * 16 + l16) * 2 + 1] * LSCALE;
  }

  const _Float16* Qt = wsh + QOFF + ((size_t)bh * 32 + qt) * 4096;
  const _Float16* Kbh = wsh + KOFF + (size_t)bh * 64 * 2048;
  const _Float16* Vbh = wsh + VOFF + (size_t)bh * 64 * 2048;
  const float* wsS = (const float*)(wsh + SOFFH);

  // staging: group = 2 waves = 128 thr; 4 KB tile = 2 rounds of 128x16B.
  // group g owns key-tiles [g*8, g*8+8) (32 keys each).
  const _Float16* ksrc = Kbh + (size_t)(g * 8) * 2048 + tg * 8;
  const _Float16* vsrc = Vbh + (size_t)(g * 8) * 2048 + tg * 8;
  char* kdst = arena + OFF_K + g * 4096 + qh * 1024;   // wave-uniform
  char* vdst = arena + OFF_V + g * 4096 + qh * 1024;
  // per-lane k-coord base: keys (g*256 + it*32 + nf*16 + quad*4 + r), 2 floats each
  const float* sbase = wsS + ((size_t)b * L_ + g * 256 + quad * 4) * 2;

  // ---- prologue: Q tile (8 KB) -> K region (waves 0..7); read qA; then loop ----
  if (w < 8)
    GLOBAL_LOAD_LDS16(Qt + w * 512 + lane * 8, arena + OFF_K + w * 1024);
  __syncthreads();  // Q landed (barrier drains vmcnt), LUT built

  half8 qA[2][2];   // [slice][kb]
#pragma unroll
  for (int s = 0; s < 2; ++s)
#pragma unroll
    for (int kb = 0; kb < 2; ++kb)
      qA[s][kb] = *(const half8*)(arena + OFF_K + ((qh * 2 + s) * 16 + l16) * 128 +
                                  ((kb * 4 + quad) ^ (l16 & 7)) * 16);
  __syncthreads();  // all qA reads done before iter-0 staging overwrites K region

  f32x4 oc[2][4];
#pragma unroll
  for (int s = 0; s < 2; ++s)
#pragma unroll
    for (int df = 0; df < 4; ++df) oc[s][df] = (f32x4){0.f, 0.f, 0.f, 0.f};
  f32x4 lsacc[2];
  lsacc[0] = (f32x4){0.f, 0.f, 0.f, 0.f};
  lsacc[1] = (f32x4){0.f, 0.f, 0.f, 0.f};
  half8 onesv;
#pragma unroll
  for (int j = 0; j < 8; ++j) onesv[j] = (_Float16)1.0f;

  for (int it = 0; it < 8; ++it) {
    // ---- stage this iter's K/V tile (single buffer; other block on CU hides drain)
    GLOBAL_LOAD_LDS16(ksrc, kdst);
    GLOBAL_LOAD_LDS16(ksrc + 1024, kdst + 2048);
    GLOBAL_LOAD_LDS16(vsrc, vdst);
    GLOBAL_LOAD_LDS16(vsrc + 1024, vdst + 2048);
    ksrc += 2048; vsrc += 2048;
    __syncthreads();  // tiles visible (barrier drains vmcnt)

    // ---- key coords (shared by both slices) ----
    const float* sit = sbase + it * 64;
    f32x4 cA = *(const f32x4*)(sit);          // nf=0: keys quad*4+0,1
    f32x4 cB = *(const f32x4*)(sit + 4);      // nf=0: keys quad*4+2,3
    f32x4 cC = *(const f32x4*)(sit + 32);     // nf=1
    f32x4 cD = *(const f32x4*)(sit + 36);
    float kx[8] = {cA.x, cA.z, cB.x, cB.z, cC.x, cC.z, cD.x, cD.z};
    float ky[8] = {cA.y, cA.w, cB.y, cB.w, cC.y, cC.w, cD.y, cD.w};

    // ---- S^T = K·Q^T: kf read ONCE, 8 MFMA (2 slices x 2 nf x 2 kb) ----
    half8 kf[2][2];
#pragma unroll
    for (int nf = 0; nf < 2; ++nf)
#pragma unroll
      for (int kb = 0; kb < 2; ++kb)
        kf[nf][kb] = *(const half8*)(arena + OFF_K + g * 4096 +
                                     (nf * 16 + l16) * 128 + ((kb * 4 + quad) ^ (l16 & 7)) * 16);
    f32x4 acc[2][2];
#pragma unroll
    for (int s = 0; s < 2; ++s)
#pragma unroll
      for (int nf = 0; nf < 2; ++nf) {
        f32x4 a = (f32x4){0.f, 0.f, 0.f, 0.f};
        a = __builtin_amdgcn_mfma_f32_16x16x32_f16(kf[nf][0], qA[s][0], a, 0, 0, 0);
        a = __builtin_amdgcn_mfma_f32_16x16x32_f16(kf[nf][1], qA[s][1], a, 0, 0, 0);
        acc[s][nf] = a;  // P[q][key'=quad*8+nf*4+r]
      }

    // ---- scores: dist -> LDS-LUT gather -> exp2; P packed in registers ----
    half8 pw[2];
#pragma unroll
    for (int s = 0; s < 2; ++s) {
      float parr[8];
#pragma unroll
      for (int j = 0; j < 8; ++j) {
        float dx = qx[s] - kx[j], dy = qy[s] - ky[j];
        float tt = FAST_SQRT(fmaf(dx, dx, dy * dy));   // = dist * LSCALE
        parr[j] = __builtin_amdgcn_exp2f(acc[s][j >> 2][j & 3] + LUT[(int)tt]);
      }
      union { half8 h8; fp16x2 h2[4]; } pu;
#pragma unroll
      for (int k = 0; k < 4; ++k)
        pu.h2[k] = __builtin_amdgcn_cvt_pkrtz(parr[2 * k], parr[2 * k + 1]);
      pw[s] = pu.h8;
    }

    // ---- PV + row-sum; vf read ONCE, used by both slices ----
    lsacc[0] = __builtin_amdgcn_mfma_f32_16x16x32_f16(pw[0], onesv, lsacc[0], 0, 0, 0);
    lsacc[1] = __builtin_amdgcn_mfma_f32_16x16x32_f16(pw[1], onesv, lsacc[1], 0, 0, 0);
#pragma unroll
    for (int df = 0; df < 4; ++df) {
      half8 vf = *(const half8*)(arena + OFF_V + g * 4096 + (l16 >> 1) * 128 + df * 1024 +
                                 ((((l16 & 1) * 4 + quad) ^ ((l16 >> 1) & 7)) * 16));
      oc[0][df] = __builtin_amdgcn_mfma_f32_16x16x32_f16(pw[0], vf, oc[0][df], 0, 0, 0);
      oc[1][df] = __builtin_amdgcn_mfma_f32_16x16x32_f16(pw[1], vf, oc[1][df], 0, 0, 0);
    }

    __syncthreads();  // buf reads done before next iter's staging overwrites
  }

  // ---- combine 8 K-groups via 3-level LDS tree (slots: (gi*4 + qh*2 + s)*SLOTF) ----
  float lred[2][4];
#pragma unroll
  for (int s = 0; s < 2; ++s)
#pragma unroll
    for (int r = 0; r < 4; ++r) lred[s][r] = lsacc[s][r];
  float* slots = (float*)arena;   // loop's trailing barrier makes arena reusable

  // level 1: groups 4..7 -> slots (g-4)
  if (g >= 4) {
#pragma unroll
    for (int s = 0; s < 2; ++s) {
      float* sl = slots + ((g - 4) * 4 + qh * 2 + s) * SLOTF;
#pragma unroll
      for (int df = 0; df < 4; ++df)
#pragma unroll
        for (int r = 0; r < 4; ++r)
          sl[(quad * 4 + r) * 68 + df * 16 + l16] = oc[s][df][r];
      if (l16 == 0) {
#pragma unroll
        for (int r = 0; r < 4; ++r) sl[16 * 68 + quad * 4 + r] = lred[s][r];
      }
    }
  }
  __syncthreads();
  if (g < 4) {
#pragma unroll
    for (int s = 0; s < 2; ++s) {
      float* sl = slots + (g * 4 + qh * 2 + s) * SLOTF;
#pragma unroll
      for (int df = 0; df < 4; ++df)
#pragma unroll
        for (int r = 0; r < 4; ++r)
          oc[s][df][r] += sl[(quad * 4 + r) * 68 + df * 16 + l16];
#pragma unroll
      for (int r = 0; r < 4; ++r) lred[s][r] += sl[16 * 68 + quad * 4 + r];
    }
  }
  __syncthreads();
  // level 2: groups 2..3 -> slots (g-2)
  if (g == 2 || g == 3) {
#pragma unroll
    for (int s = 0; s < 2; ++s) {
      float* sl = slots + ((g - 2) * 4 + qh * 2 + s) * SLOTF;
#pragma unroll
      for (int df = 0; df < 4; ++df)
#pragma unroll
        for (int r = 0; r < 4; ++r)
          sl[(quad * 4 + r) * 68 + df * 16 + l16] = oc[s][df][r];
      if (l16 == 0) {
#pragma unroll
        for (int r = 0; r < 4; ++r) sl[16 * 68 + quad * 4 + r] = lred[s][r];
      }
    }
  }
  __syncthreads();
  if (g < 2) {
#pragma unroll
    for (int s = 0; s < 2; ++s) {
      float* sl = slots + (g * 4 + qh * 2 + s) * SLOTF;
#pragma unroll
      for (int df = 0; df < 4; ++df)
#pragma unroll
        for (int r = 0; r < 4; ++r)
          oc[s][df][r] += sl[(quad * 4 + r) * 68 + df * 16 + l16];
#pragma unroll
      for (int r = 0; r < 4; ++r) lred[s][r] += sl[16 * 68 + quad * 4 + r];
    }
  }
  __syncthreads();
  // level 3: group 1 -> slots 0
  if (g == 1) {
#pragma unroll
    for (int s = 0; s < 2; ++s) {
      float* sl = slots + (qh * 2 + s) * SLOTF;
#pragma unroll
      for (int df = 0; df < 4; ++df)
#pragma unroll
        for (int r = 0; r < 4; ++r)
          sl[(quad * 4 + r) * 68 + df * 16 + l16] = oc[s][df][r];
      if (l16 == 0) {
#pragma unroll
        for (int r = 0; r < 4; ++r) sl[16 * 68 + quad * 4 + r] = lred[s][r];
      }
    }
  }
  __syncthreads();
  if (g == 0) {
#pragma unroll
    for (int s = 0; s < 2; ++s) {
      float* sl = slots + (qh * 2 + s) * SLOTF;
      float inv_l[4];
#pragma unroll
      for (int r = 0; r < 4; ++r)
        inv_l[r] = 1.f / (lred[s][r] + sl[16 * 68 + quad * 4 + r]);
#pragma unroll
      for (int df = 0; df < 4; ++df)
#pragma unroll
        for (int r = 0; r < 4; ++r) {
          int qrow = q0 + (qh * 2 + s) * 16 + quad * 4 + r;
          float v = oc[s][df][r] + sl[(quad * 4 + r) * 68 + df * 16 + l16];
          out[((size_t)(b * L_ + qrow)) * (H_ * D_) + h * D_ + df * 16 + l16] = v * inv_l[r];
        }
    }
  }
}

// ---------------- fallback (R3 kernel) if ws too small ----------------
#define KSTR 72
#define PH 72
#define FLUTN 512
#define FLSCALE 362.03867f
__global__ __launch_bounds__(512, 4)
void tisa_attn_fallback(const float* __restrict__ qs, const float* __restrict__ ks,
                        const float* __restrict__ vs, const float* __restrict__ qs_s,
                        const float* __restrict__ ks_s, const float* __restrict__ ap,
                        const float* __restrict__ bp, const float* __restrict__ cp,
                        float* __restrict__ out) {
  __shared__ _Float16 Ks[2][64 * KSTR];
  __shared__ _Float16 VT[2][D_ * KSTR];
  __shared__ _Float16 Pf[8][16 * PH];
  __shared__ float kss2[2][64 * 2];
  __shared__ f32x2 LUT2s[FLUTN + 1];
  __shared__ float comb[4][16][64];
  __shared__ float combl[4][16];

  const int t = threadIdx.x;
  const int lane = t & 63;
  const int w = t >> 6;
  const int g = w >> 2;
  const int qw = w & 3;
  const int t2 = t & 255;
  const int quad = lane >> 4;
  const int l16 = lane & 15;
  const int qt = blockIdx.x & 31;
  const int bh = blockIdx.x >> 5;
  const int h = bh & 7;
  const int b = bh >> 3;
  const int q0 = qt * 64;

  float af[F_], nb[F_], cf[F_];
#pragma unroll
  for (int f = 0; f < F_; ++f) {
    af[f] = ap[h * F_ + f];
    nb[f] = -fabsf(bp[h * F_ + f]);
    cf[f] = cp[h * F_ + f];
  }
  for (int i = t; i <= FLUTN; i += 512) {
    float d0 = (float)i * (1.0f / FLSCALE), d1 = (float)(i + 1) * (1.0f / FLSCALE);
    float s0 = 0.f, s1 = 0.f;
#pragma unroll
    for (int f = 0; f < F_; ++f) {
      float e0 = d0 - cf[f], e1 = d1 - cf[f];
      s0 += af[f] * __expf(nb[f] * (e0 * e0));
      s1 += af[f] * __expf(nb[f] * (e1 * e1));
    }
    LUT2s[i] = (f32x2){s0 - 8.0f, s1 - 8.0f};
  }
  float qx[4], qy[4];
#pragma unroll
  for (int r = 0; r < 4; ++r) {
    int qrow = q0 + qw * 16 + quad * 4 + r;
    qx[r] = qs_s[(b * L_ + qrow) * S_ + 0];
    qy[r] = qs_s[(b * L_ + qrow) * S_ + 1];
  }
  if (t < 256) {
    const int row = t >> 2, dc = (t & 3) * 16;
    const float* src = qs + (((size_t)(b * L_ + q0 + row)) * H_ + h) * D_ + dc;
    const f32x4* s4 = (const f32x4*)src;
    f32x4 v0 = s4[0], v1 = s4[1], v2 = s4[2], v3 = s4[3];
    half8 w0, w1;
#pragma unroll
    for (int u = 0; u < 4; ++u) {
      w0[u] = (_Float16)(v0[u] * 0.125f); w0[u + 4] = (_Float16)(v1[u] * 0.125f);
      w1[u] = (_Float16)(v2[u] * 0.125f); w1[u + 4] = (_Float16)(v3[u] * 0.125f);
    }
    *(half8*)&Ks[0][row * KSTR + dc] = w0;
    *(half8*)&Ks[0][row * KSTR + dc + 8] = w1;
  }
  __syncthreads();
  half8 qA[2];
#pragma unroll
  for (int kb = 0; kb < 2; ++kb)
    qA[kb] = *(const half8*)&Ks[0][(qw * 16 + l16) * KSTR + kb * 32 + quad * 8];
  f32x4 oc[4];
#pragma unroll
  for (int df = 0; df < 4; ++df) oc[df] = (f32x4){0.f, 0.f, 0.f, 0.f};
  float l_r[4] = {0.f, 0.f, 0.f, 0.f};

  for (int it = 0; it < 16; ++it) {
    const int k0 = (g * 16 + it) * 64;
    __syncthreads();
    {
      const int row = t2 >> 2, dc = (t2 & 3) * 16;
      const float* src = ks + (((size_t)(b * L_ + k0 + row)) * H_ + h) * D_ + dc;
      const f32x4* s4 = (const f32x4*)src;
      f32x4 v0 = s4[0], v1 = s4[1], v2 = s4[2], v3 = s4[3];
      half8 w0, w1;
#pragma unroll
      for (int u = 0; u < 4; ++u) {
        w0[u] = (_Float16)v0[u]; w0[u + 4] = (_Float16)v1[u];
        w1[u] = (_Float16)v2[u]; w1[u + 4] = (_Float16)v3[u];
      }
      *(half8*)&Ks[g][row * KSTR + dc] = w0;
      *(half8*)&Ks[g][row * KSTR + dc + 8] = w1;
    }
    {
      const int kk = (t2 & 31) * 2, dg = (t2 >> 5) * 8;
      const float* s0 = vs + (((size_t)(b * L_ + k0 + kk)) * H_ + h) * D_ + dg;
      const float* s1 = s0 + H_ * D_;
      f32x4 a0 = ((const f32x4*)s0)[0], a1 = ((const f32x4*)s0)[1];
      f32x4 b0 = ((const f32x4*)s1)[0], b1 = ((const f32x4*)s1)[1];
#pragma unroll
      for (int u = 0; u < 4; ++u) {
        half2v p0 = {(_Float16)a0[u], (_Float16)b0[u]};
        *(half2v*)&VT[g][(dg + u) * KSTR + kk] = p0;
        half2v p1 = {(_Float16)a1[u], (_Float16)b1[u]};
        *(half2v*)&VT[g][(dg + 4 + u) * KSTR + kk] = p1;
      }
    }
    if (t2 < 128) kss2[g][t2] = ks_s[((size_t)(b * L_) + k0 + (t2 >> 1)) * S_ + (t2 & 1)];
    __syncthreads();
    f32x4 acc[4];
#pragma unroll
    for (int nf = 0; nf < 4; ++nf) {
      f32x4 a = (f32x4){0.f, 0.f, 0.f, 0.f};
#pragma unroll
      for (int kb = 0; kb < 2; ++kb) {
        half8 kf = *(const half8*)&Ks[g][(nf * 16 + l16) * KSTR + kb * 32 + quad * 8];
        a = __builtin_amdgcn_mfma_f32_16x16x32_f16(qA[kb], kf, a, 0, 0, 0);
      }
      acc[nf] = a;
    }
#pragma unroll
    for (int nf = 0; nf < 4; ++nf) {
      float kx = kss2[g][(nf * 16 + l16) * 2 + 0];
      float ky = kss2[g][(nf * 16 + l16) * 2 + 1];
#pragma unroll
      for (int r = 0; r < 4; ++r) {
        float dx = qx[r] - kx, dy = qy[r] - ky;
        float dist = FAST_SQRT(fmaf(dx, dx, dy * dy));
        float tt = dist * FLSCALE;
        int ii = (int)tt;
        float fr = tt - (float)ii;
        f32x2 lh = LUT2s[ii];
        float p = __expf(acc[nf][r] + fmaf(fr, lh.y - lh.x, lh.x));
        acc[nf][r] = p;
      }
    }
#pragma unroll
    for (int r = 0; r < 4; ++r)
      l_r[r] += (acc[0][r] + acc[1][r]) + (acc[2][r] + acc[3][r]);
#pragma unroll
    for (int nf = 0; nf < 4; ++nf)
#pragma unroll
      for (int r = 0; r < 4; ++r)
        Pf[w][(quad * 4 + r) * PH + nf * 16 + l16] = (_Float16)acc[nf][r];
#pragma unroll
    for (int kb = 0; kb < 2; ++kb) {
      half8 pa = *(const half8*)&Pf[w][l16 * PH + kb * 32 + quad * 8];
#pragma unroll
      for (int df = 0; df < 4; ++df) {
        half8 vf = *(const half8*)&VT[g][(df * 16 + l16) * KSTR + kb * 32 + quad * 8];
        oc[df] = __builtin_amdgcn_mfma_f32_16x16x32_f16(pa, vf, oc[df], 0, 0, 0);
      }
    }
  }
  __syncthreads();
  float lred[4];
#pragma unroll
  for (int r = 0; r < 4; ++r) {
    float s = l_r[r];
    s += __shfl_xor(s, 1); s += __shfl_xor(s, 2);
    s += __shfl_xor(s, 4); s += __shfl_xor(s, 8);
    lred[r] = s;
  }
  if (g == 1) {
#pragma unroll
    for (int df = 0; df < 4; ++df)
#pragma unroll
      for (int r = 0; r < 4; ++r)
        comb[qw][quad * 4 + r][df * 16 + l16] = oc[df][r];
    if (l16 == 0) {
#pragma unroll
      for (int r = 0; r < 4; ++r) combl[qw][quad * 4 + r] = lred[r];
    }
  }
  __syncthreads();
  if (g == 0) {
    float inv_l[4];
#pragma unroll
    for (int r = 0; r < 4; ++r)
      inv_l[r] = 1.f / (lred[r] + combl[qw][quad * 4 + r]);
#pragma unroll
    for (int df = 0; df < 4; ++df)
#pragma unroll
      for (int r = 0; r < 4; ++r) {
        int qrow = q0 + qw * 16 + quad * 4 + r;
        float v = oc[df][r] + combl[qw][quad * 4 + r] * 0.f + comb[qw][quad * 4 + r][df * 16 + l16];
        out[(((size_t)(b * L_ + qrow)) * H_ + h) * D_ + df * 16 + l16] = v * inv_l[r];
      }
  }
}

extern "C" void kernel_launch(void* const* d_in, const int* in_sizes, int n_in,
                              void* d_out, int out_size, void* d_ws, size_t ws_size,
                              hipStream_t stream) {
  const float* qs = (const float*)d_in[0];
  const float* ks = (const float*)d_in[1];
  const float* vs = (const float*)d_in[2];
  const float* qs_s = (const float*)d_in[3];
  const float* ks_s = (const float*)d_in[4];
  const float* ap = (const float*)d_in[5];
  const float* bp = (const float*)d_in[6];
  const float* cp = (const float*)d_in[7];
  float* out = (float*)d_out;

  if (ws_size >= (size_t)WS_NEED) {
    _Float16* wsh = (_Float16*)d_ws;
    tisa_preproc<<<dim3(512), dim3(512), 0, stream>>>(qs, ks, vs, ks_s, wsh);
    tisa_attn_main<<<dim3(512), dim3(1024), 0, stream>>>(qs_s, ap, bp, cp, wsh, out);
  } else {
    tisa_attn_fallback<<<dim3(512), dim3(512), 0, stream>>>(qs, ks, vs, qs_s, ks_s, ap, bp, cp, out);
  }
}

// Round 10
// 128.279 us; speedup vs baseline: 2.7845x; 2.7845x over previous
//
#include <hip/hip_runtime.h>
#include <cmath>

typedef _Float16 half8 __attribute__((ext_vector_type(8)));
typedef _Float16 half4 __attribute__((ext_vector_type(4)));
typedef _Float16 half2v __attribute__((ext_vector_type(2)));
typedef __fp16 fp16x2 __attribute__((ext_vector_type(2)));   // cvt_pkrtz return type
typedef float f32x4 __attribute__((ext_vector_type(4)));
typedef float f32x2 __attribute__((ext_vector_type(2)));

#define B_ 2
#define L_ 2048
#define H_ 8
#define D_ 64
#define S_ 2
#define F_ 5
#define LUTN 2048
#define LSCALE 1448.1547f          // LUTN / sqrt(2)
#define LOG2E 1.44269504f
#define QSC (0.125f * LOG2E)       // folded into Q at preprocess

// ws layout: Q tiles (64x64 f16, swizzled), K tiles (32x64 f16, swizzled),
// VT tiles (superrow-swizzled f16, KEY-PERMUTED for register-resident P),
// then pre-scaled ks_s coords (f32).
#define QOFF 0            // halfs
#define KOFF 2097152      // halfs
#define VOFF 4194304      // halfs
#define SOFFH 6291456     // halfs -> (float*)(wsh + SOFFH)
#define WS_NEED 12615680  // bytes

// main-kernel LDS arena: EXACTLY 40960 B so 4 blocks fit the 160 KiB CU LDS.
// Single-buffered K/V (prefetch proven null in R2; 3 sibling blocks hide the
// stage drain) + 2048-entry LUT (index <= 2047 guaranteed: dist < sqrt(2)).
#define OFF_K 0            // 4 groups x 4096
#define OFF_V 16384        // 4 groups x 4096
#define OFF_LUT 32768      // 2048 x 4 = 8192
#define ARENA_SZ 40960     // 4 blocks/CU x 8 waves = 32 waves/CU (VGPR 64 allows 32)
#define SLOTF (16 * 68 + 16)   // combine slot: O[16][68] f32 + l[16] (8 slots = 35 KB < arena)

#define GLOBAL_LOAD_LDS16(g, l)                                                  \
  __builtin_amdgcn_global_load_lds((const __attribute__((address_space(1))) void*)(g), \
                                   (__attribute__((address_space(3))) void*)(l), 16, 0, 0)

// raw v_sqrt_f32 (1 ULP) — result only feeds a 2048-bin LUT quantizer.
#define FAST_SQRT(x) __builtin_amdgcn_sqrtf(x)

// ---------------- preprocessing: f32 -> f16 swizzled tiles in ws ----------------
// (R8 version, unchanged) grid 512 x 512 thr: (bh,u) per block.
#define VTS 68   // VT row stride in halfs (34 dwords; odd dword stride -> spread)
__global__ __launch_bounds__(512, 8)
void tisa_preproc(const float* __restrict__ qs, const float* __restrict__ ks,
                  const float* __restrict__ vs, const float* __restrict__ ks_s,
                  _Float16* __restrict__ wsh) {
  __shared__ _Float16 VT[64 * VTS];   // [d 64][key 64 (+4 pad)]
  const int t = threadIdx.x;
  const int bid = blockIdx.x;
  const int xcd = bid & 7, slot = bid >> 3;
  const int u = slot & 31;
  const int bh = xcd * 2 + (slot >> 5);
  const size_t base = ((size_t)(bh >> 3) * L_ + (size_t)u * 64) * (H_ * D_) + (size_t)(bh & 7) * D_;

  // ---- Q: 512 chunks of 8 f32 -> 8 f16, swizzled chunk c^(row&7), scaled by QSC ----
  {
    int row = t >> 3, c = t & 7;
    const float* src = qs + base + (size_t)row * 512 + c * 8;
    f32x4 x0 = ((const f32x4*)src)[0], x1 = ((const f32x4*)src)[1];
    half8 hh;
#pragma unroll
    for (int k = 0; k < 4; ++k) { hh[k] = (_Float16)(x0[k] * QSC); hh[k + 4] = (_Float16)(x1[k] * QSC); }
    *(half8*)&wsh[QOFF + ((size_t)bh * 32 + u) * 4096 + row * 64 + (c ^ (row & 7)) * 8] = hh;
  }
  // ---- K: two 32-row tiles, same chunk swizzle ----
  {
    int tile = t >> 8, row = (t >> 3) & 31, c = t & 7;
    const float* src = ks + base + (size_t)(tile * 32 + row) * 512 + c * 8;
    f32x4 x0 = ((const f32x4*)src)[0], x1 = ((const f32x4*)src)[1];
    half8 hh;
#pragma unroll
    for (int k = 0; k < 4; ++k) { hh[k] = (_Float16)x0[k]; hh[k + 4] = (_Float16)x1[k]; }
    *(half8*)&wsh[KOFF + ((size_t)bh * 64 + u * 2 + tile) * 2048 + row * 64 + (c ^ (row & 7)) * 8] = hh;
  }
  // ---- scaled ks_s coords (h==0 blocks only; 64 keys = 128 floats) ----
  if ((bh & 7) == 0 && t < 32) {
    const int b = bh >> 3;
    const float* src = ks_s + ((size_t)b * L_ + u * 64) * 2 + t * 4;
    float* dst = (float*)(wsh + SOFFH) + ((size_t)b * L_ + u * 64) * 2 + t * 4;
    f32x4 x = *(const f32x4*)src;
    x *= LSCALE;
    *(f32x4*)dst = x;
  }
  // ---- V: register transpose -> VT[d][key] (threads 0..255: 2 keys x 8 d) ----
  if (t < 256) {
    int kk = (t & 31) * 2, dg = (t >> 5) * 8;
    const float* s0 = vs + base + (size_t)kk * 512 + dg;
    const float* s1 = s0 + 512;
    f32x4 a0 = ((const f32x4*)s0)[0], a1 = ((const f32x4*)s0)[1];
    f32x4 b0 = ((const f32x4*)s1)[0], b1 = ((const f32x4*)s1)[1];
#pragma unroll
    for (int v = 0; v < 4; ++v) {
      half2v p0 = {(_Float16)a0[v], (_Float16)b0[v]};
      *(half2v*)&VT[(dg + v) * VTS + kk] = p0;
      half2v p1 = {(_Float16)a1[v], (_Float16)b1[v]};
      *(half2v*)&VT[(dg + 4 + v) * VTS + kk] = p1;
    }
  }
  __syncthreads();
  // ---- gather key'-ordered half8 from VT rows (2x contiguous b64), write ws ----
  {
    int tile = t >> 8, s = (t >> 3) & 31, cp2 = t & 7;
    int d = 2 * s + (cp2 >> 2), qp = cp2 & 3;
    half4 lo = *(const half4*)&VT[d * VTS + tile * 32 + qp * 4];        // nf=0
    half4 hi = *(const half4*)&VT[d * VTS + tile * 32 + 16 + qp * 4];   // nf=1
    half8 hh;
#pragma unroll
    for (int j = 0; j < 4; ++j) { hh[j] = lo[j]; hh[j + 4] = hi[j]; }
    *(half8*)&wsh[VOFF + ((size_t)bh * 64 + u * 2 + tile) * 2048 + s * 64 + (cp2 ^ (s & 7)) * 8] = hh;
  }
}

// ---------------- main kernel: 512 thr = 8 waves = 4 K-quarters x 2 q-halves ---------
// R7 structure (N_rep=2, VGPR=64, 46.3 us at 2 blocks/CU), single-buffered so the
// arena is 40960 B -> 4 blocks/CU = 32 waves/CU (occupancy was the R8 limiter).
// launch_bounds(512,4) empirically yields exactly 64 VGPRs on this kernel.
__global__ __launch_bounds__(512, 4)
void tisa_attn_main(const float* __restrict__ qs_s, const float* __restrict__ ap,
                    const float* __restrict__ bp, const float* __restrict__ cp,
                    const _Float16* __restrict__ wsh, float* __restrict__ out) {
  __shared__ __align__(16) char arena[ARENA_SZ];
  float* LUT = (float*)(arena + OFF_LUT);

  const int t = threadIdx.x;
  const int lane = t & 63;
  const int w = t >> 6;       // 0..7
  const int g = w >> 1;       // K-quarter 0..3
  const int qh = w & 1;       // q-half 0..1 (owns q-slices 2qh, 2qh+1)
  const int tg = t & 127;     // index within group (2 waves)
  const int quad = lane >> 4;
  const int l16 = lane & 15;

  // XCD swizzle: each XCD gets a contiguous bh-pair -> K/V stays L2-resident.
  const int bid = blockIdx.x;
  const int xcd = bid & 7, slot = bid >> 3;
  const int qt = slot & 31;
  const int bh = xcd * 2 + (slot >> 5);
  const int h = bh & 7;
  const int b = bh >> 3;
  const int q0 = qt * 64;

  // ---- LUT (nearest-neighbor, midpoint-sampled): ((bias-8)*log2e) at d=(i+0.5)/LSCALE
  //      2048 entries; index <= 2047 guaranteed (dist < sqrt(2)), fminf clamp below.
  {
    float af[F_], nb[F_], cf[F_];
#pragma unroll
    for (int f = 0; f < F_; ++f) {
      af[f] = ap[h * F_ + f];
      nb[f] = -fabsf(bp[h * F_ + f]);
      cf[f] = cp[h * F_ + f];
    }
    for (int i = t; i < LUTN; i += 512) {
      float d = ((float)i + 0.5f) * (1.0f / LSCALE);
      float s = 0.f;
#pragma unroll
      for (int f = 0; f < F_; ++f) {
        float e = d - cf[f];
        s += af[f] * __expf(nb[f] * (e * e));
      }
      LUT[i] = (s - 8.0f) * LOG2E;
    }
  }

  // q coords for this lane's two S^T columns (q = (2qh+s)*16 + l16), pre-scaled
  float qx[2], qy[2];
#pragma unroll
  for (int s = 0; s < 2; ++s) {
    qx[s] = qs_s[((size_t)b * L_ + q0 + (qh * 2 + s) * 16 + l16) * 2 + 0] * LSCALE;
    qy[s] = qs_s[((size_t)b * L_ + q0 + (qh * 2 + s) * 16 + l16) * 2 + 1] * LSCALE;
  }

  const _Float16* Qt = wsh + QOFF + ((size_t)bh * 32 + qt) * 4096;
  const _Float16* Kbh = wsh + KOFF + (size_t)bh * 64 * 2048;
  const _Float16* Vbh = wsh + VOFF + (size_t)bh * 64 * 2048;
  const float* wsS = (const float*)(wsh + SOFFH);

  // staging: group = 2 waves = 128 thr; 4 KB tile = 2 rounds of 128x16B
  const _Float16* ksrc = Kbh + (size_t)(g * 16) * 2048 + tg * 8;
  const _Float16* vsrc = Vbh + (size_t)(g * 16) * 2048 + tg * 8;
  char* kdst = arena + OFF_K + g * 4096 + qh * 1024;   // wave-uniform
  char* vdst = arena + OFF_V + g * 4096 + qh * 1024;
  // per-lane k-coord base: keys (g*512 + it*32 + nf*16 + quad*4 + r), 2 floats each
  const float* sbase = wsS + ((size_t)b * L_ + g * 512 + quad * 4) * 2;

  // ---- prologue: Q tile (8 KB) -> K region (all 8 waves); read qA ----
  GLOBAL_LOAD_LDS16(Qt + w * 512 + lane * 8, arena + OFF_K + w * 1024);
  __syncthreads();  // Q landed (barrier drains vmcnt), LUT built

  half8 qA[2][2];   // [slice][kb]
#pragma unroll
  for (int s = 0; s < 2; ++s)
#pragma unroll
    for (int kb = 0; kb < 2; ++kb)
      qA[s][kb] = *(const half8*)(arena + OFF_K + ((qh * 2 + s) * 16 + l16) * 128 +
                                  ((kb * 4 + quad) ^ (l16 & 7)) * 16);
  __syncthreads();  // qA reads done before iter-0 staging overwrites K region

  f32x4 oc[2][4];
#pragma unroll
  for (int s = 0; s < 2; ++s)
#pragma unroll
    for (int df = 0; df < 4; ++df) oc[s][df] = (f32x4){0.f, 0.f, 0.f, 0.f};
  f32x4 lsacc[2];
  lsacc[0] = (f32x4){0.f, 0.f, 0.f, 0.f};
  lsacc[1] = (f32x4){0.f, 0.f, 0.f, 0.f};
  half8 onesv;
#pragma unroll
  for (int j = 0; j < 8; ++j) onesv[j] = (_Float16)1.0f;

  for (int it = 0; it < 16; ++it) {
    // ---- stage this iter's K/V tile (single buffer; 3 sibling blocks hide drain)
    GLOBAL_LOAD_LDS16(ksrc, kdst);
    GLOBAL_LOAD_LDS16(ksrc + 1024, kdst + 2048);
    GLOBAL_LOAD_LDS16(vsrc, vdst);
    GLOBAL_LOAD_LDS16(vsrc + 1024, vdst + 2048);
    ksrc += 2048; vsrc += 2048;
    __syncthreads();  // tiles visible (barrier drains vmcnt)

    // ---- key coords (shared by both slices) ----
    const float* sit = sbase + it * 64;
    f32x4 cA = *(const f32x4*)(sit);          // nf=0: keys quad*4+0,1
    f32x4 cB = *(const f32x4*)(sit + 4);      // nf=0: keys quad*4+2,3
    f32x4 cC = *(const f32x4*)(sit + 32);     // nf=1
    f32x4 cD = *(const f32x4*)(sit + 36);
    float kx[8] = {cA.x, cA.z, cB.x, cB.z, cC.x, cC.z, cD.x, cD.z};
    float ky[8] = {cA.y, cA.w, cB.y, cB.w, cC.y, cC.w, cD.y, cD.w};

    // ---- S^T = K·Q^T: kf read ONCE, 8 MFMA (2 slices x 2 nf x 2 kb) ----
    half8 kf[2][2];
#pragma unroll
    for (int nf = 0; nf < 2; ++nf)
#pragma unroll
      for (int kb = 0; kb < 2; ++kb)
        kf[nf][kb] = *(const half8*)(arena + OFF_K + g * 4096 +
                                     (nf * 16 + l16) * 128 + ((kb * 4 + quad) ^ (l16 & 7)) * 16);
    f32x4 acc[2][2];
#pragma unroll
    for (int s = 0; s < 2; ++s)
#pragma unroll
      for (int nf = 0; nf < 2; ++nf) {
        f32x4 a = (f32x4){0.f, 0.f, 0.f, 0.f};
        a = __builtin_amdgcn_mfma_f32_16x16x32_f16(kf[nf][0], qA[s][0], a, 0, 0, 0);
        a = __builtin_amdgcn_mfma_f32_16x16x32_f16(kf[nf][1], qA[s][1], a, 0, 0, 0);
        acc[s][nf] = a;  // P[q][key'=quad*8+nf*4+r]
      }

    // ---- scores: dist -> LDS-LUT gather -> exp2; P packed in registers ----
    half8 pw[2];
#pragma unroll
    for (int s = 0; s < 2; ++s) {
      float parr[8];
#pragma unroll
      for (int j = 0; j < 8; ++j) {
        float dx = qx[s] - kx[j], dy = qy[s] - ky[j];
        float tt = fminf(FAST_SQRT(fmaf(dx, dx, dy * dy)), 2047.0f);  // = dist*LSCALE
        parr[j] = __builtin_amdgcn_exp2f(acc[s][j >> 2][j & 3] + LUT[(int)tt]);
      }
      union { half8 h8; fp16x2 h2[4]; } pu;
#pragma unroll
      for (int k = 0; k < 4; ++k)
        pu.h2[k] = __builtin_amdgcn_cvt_pkrtz(parr[2 * k], parr[2 * k + 1]);
      pw[s] = pu.h8;
    }

    // ---- PV + row-sum; vf read ONCE, used by both slices ----
    lsacc[0] = __builtin_amdgcn_mfma_f32_16x16x32_f16(pw[0], onesv, lsacc[0], 0, 0, 0);
    lsacc[1] = __builtin_amdgcn_mfma_f32_16x16x32_f16(pw[1], onesv, lsacc[1], 0, 0, 0);
#pragma unroll
    for (int df = 0; df < 4; ++df) {
      half8 vf = *(const half8*)(arena + OFF_V + g * 4096 + (l16 >> 1) * 128 + df * 1024 +
                                 ((((l16 & 1) * 4 + quad) ^ ((l16 >> 1) & 7)) * 16));
      oc[0][df] = __builtin_amdgcn_mfma_f32_16x16x32_f16(pw[0], vf, oc[0][df], 0, 0, 0);
      oc[1][df] = __builtin_amdgcn_mfma_f32_16x16x32_f16(pw[1], vf, oc[1][df], 0, 0, 0);
    }

    __syncthreads();  // buf reads done before next iter's staging overwrites
  }

  // ---- combine 4 K-quarters via LDS tree (row sums already reduced by ones-MFMA) ----
  float lred[2][4];
#pragma unroll
  for (int s = 0; s < 2; ++s)
#pragma unroll
    for (int r = 0; r < 4; ++r) lred[s][r] = lsacc[s][r];
  float* slots = (float*)arena;   // loop's trailing barrier makes arena reusable
  if (g >= 2) {
#pragma unroll
    for (int s = 0; s < 2; ++s) {
      float* sl = slots + ((g - 2) * 4 + qh * 2 + s) * SLOTF;
#pragma unroll
      for (int df = 0; df < 4; ++df)
#pragma unroll
        for (int r = 0; r < 4; ++r)
          sl[(quad * 4 + r) * 68 + df * 16 + l16] = oc[s][df][r];
      if (l16 == 0) {
#pragma unroll
        for (int r = 0; r < 4; ++r) sl[16 * 68 + quad * 4 + r] = lred[s][r];
      }
    }
  }
  __syncthreads();
  if (g < 2) {
#pragma unroll
    for (int s = 0; s < 2; ++s) {
      float* sl = slots + (g * 4 + qh * 2 + s) * SLOTF;   // g0<-slot(g2), g1<-slot(g3)
#pragma unroll
      for (int df = 0; df < 4; ++df)
#pragma unroll
        for (int r = 0; r < 4; ++r)
          oc[s][df][r] += sl[(quad * 4 + r) * 68 + df * 16 + l16];
#pragma unroll
      for (int r = 0; r < 4; ++r) lred[s][r] += sl[16 * 68 + quad * 4 + r];
    }
  }
  if (g == 1) {  // write combined back into same slot (same-wave, in-order)
#pragma unroll
    for (int s = 0; s < 2; ++s) {
      float* sl = slots + (4 + qh * 2 + s) * SLOTF;
#pragma unroll
      for (int df = 0; df < 4; ++df)
#pragma unroll
        for (int r = 0; r < 4; ++r)
          sl[(quad * 4 + r) * 68 + df * 16 + l16] = oc[s][df][r];
      if (l16 == 0) {
#pragma unroll
        for (int r = 0; r < 4; ++r) sl[16 * 68 + quad * 4 + r] = lred[s][r];
      }
    }
  }
  __syncthreads();
  if (g == 0) {
#pragma unroll
    for (int s = 0; s < 2; ++s) {
      float* sl = slots + (4 + qh * 2 + s) * SLOTF;
      float inv_l[4];
#pragma unroll
      for (int r = 0; r < 4; ++r)
        inv_l[r] = 1.f / (lred[s][r] + sl[16 * 68 + quad * 4 + r]);
#pragma unroll
      for (int df = 0; df < 4; ++df)
#pragma unroll
        for (int r = 0; r < 4; ++r) {
          int qrow = q0 + (qh * 2 + s) * 16 + quad * 4 + r;
          float v = oc[s][df][r] + sl[(quad * 4 + r) * 68 + df * 16 + l16];
          out[((size_t)(b * L_ + qrow)) * (H_ * D_) + h * D_ + df * 16 + l16] = v * inv_l[r];
        }
    }
  }
}

// ---------------- fallback (R3 kernel) if ws too small ----------------
#define KSTR 72
#define PH 72
#define FLUTN 512
#define FLSCALE 362.03867f
__global__ __launch_bounds__(512, 4)
void tisa_attn_fallback(const float* __restrict__ qs, const float* __restrict__ ks,
                        const float* __restrict__ vs, const float* __restrict__ qs_s,
                        const float* __restrict__ ks_s, const float* __restrict__ ap,
                        const float* __restrict__ bp, const float* __restrict__ cp,
                        float* __restrict__ out) {
  __shared__ _Float16 Ks[2][64 * KSTR];
  __shared__ _Float16 VT[2][D_ * KSTR];
  __shared__ _Float16 Pf[8][16 * PH];
  __shared__ float kss2[2][64 * 2];
  __shared__ f32x2 LUT2s[FLUTN + 1];
  __shared__ float comb[4][16][64];
  __shared__ float combl[4][16];

  const int t = threadIdx.x;
  const int lane = t & 63;
  const int w = t >> 6;
  const int g = w >> 2;
  const int qw = w & 3;
  const int t2 = t & 255;
  const int quad = lane >> 4;
  const int l16 = lane & 15;
  const int qt = blockIdx.x & 31;
  const int bh = blockIdx.x >> 5;
  const int h = bh & 7;
  const int b = bh >> 3;
  const int q0 = qt * 64;

  float af[F_], nb[F_], cf[F_];
#pragma unroll
  for (int f = 0; f < F_; ++f) {
    af[f] = ap[h * F_ + f];
    nb[f] = -fabsf(bp[h * F_ + f]);
    cf[f] = cp[h * F_ + f];
  }
  for (int i = t; i <= FLUTN; i += 512) {
    float d0 = (float)i * (1.0f / FLSCALE), d1 = (float)(i + 1) * (1.0f / FLSCALE);
    float s0 = 0.f, s1 = 0.f;
#pragma unroll
    for (int f = 0; f < F_; ++f) {
      float e0 = d0 - cf[f], e1 = d1 - cf[f];
      s0 += af[f] * __expf(nb[f] * (e0 * e0));
      s1 += af[f] * __expf(nb[f] * (e1 * e1));
    }
    LUT2s[i] = (f32x2){s0 - 8.0f, s1 - 8.0f};
  }
  float qx[4], qy[4];
#pragma unroll
  for (int r = 0; r < 4; ++r) {
    int qrow = q0 + qw * 16 + quad * 4 + r;
    qx[r] = qs_s[(b * L_ + qrow) * S_ + 0];
    qy[r] = qs_s[(b * L_ + qrow) * S_ + 1];
  }
  if (t < 256) {
    const int row = t >> 2, dc = (t & 3) * 16;
    const float* src = qs + (((size_t)(b * L_ + q0 + row)) * H_ + h) * D_ + dc;
    const f32x4* s4 = (const f32x4*)src;
    f32x4 v0 = s4[0], v1 = s4[1], v2 = s4[2], v3 = s4[3];
    half8 w0, w1;
#pragma unroll
    for (int u = 0; u < 4; ++u) {
      w0[u] = (_Float16)(v0[u] * 0.125f); w0[u + 4] = (_Float16)(v1[u] * 0.125f);
      w1[u] = (_Float16)(v2[u] * 0.125f); w1[u + 4] = (_Float16)(v3[u] * 0.125f);
    }
    *(half8*)&Ks[0][row * KSTR + dc] = w0;
    *(half8*)&Ks[0][row * KSTR + dc + 8] = w1;
  }
  __syncthreads();
  half8 qA[2];
#pragma unroll
  for (int kb = 0; kb < 2; ++kb)
    qA[kb] = *(const half8*)&Ks[0][(qw * 16 + l16) * KSTR + kb * 32 + quad * 8];
  f32x4 oc[4];
#pragma unroll
  for (int df = 0; df < 4; ++df) oc[df] = (f32x4){0.f, 0.f, 0.f, 0.f};
  float l_r[4] = {0.f, 0.f, 0.f, 0.f};

  for (int it = 0; it < 16; ++it) {
    const int k0 = (g * 16 + it) * 64;
    __syncthreads();
    {
      const int row = t2 >> 2, dc = (t2 & 3) * 16;
      const float* src = ks + (((size_t)(b * L_ + k0 + row)) * H_ + h) * D_ + dc;
      const f32x4* s4 = (const f32x4*)src;
      f32x4 v0 = s4[0], v1 = s4[1], v2 = s4[2], v3 = s4[3];
      half8 w0, w1;
#pragma unroll
      for (int u = 0; u < 4; ++u) {
        w0[u] = (_Float16)v0[u]; w0[u + 4] = (_Float16)v1[u];
        w1[u] = (_Float16)v2[u]; w1[u + 4] = (_Float16)v3[u];
      }
      *(half8*)&Ks[g][row * KSTR + dc] = w0;
      *(half8*)&Ks[g][row * KSTR + dc + 8] = w1;
    }
    {
      const int kk = (t2 & 31) * 2, dg = (t2 >> 5) * 8;
      const float* s0 = vs + (((size_t)(b * L_ + k0 + kk)) * H_ + h) * D_ + dg;
      const float* s1 = s0 + H_ * D_;
      f32x4 a0 = ((const f32x4*)s0)[0], a1 = ((const f32x4*)s0)[1];
      f32x4 b0 = ((const f32x4*)s1)[0], b1 = ((const f32x4*)s1)[1];
#pragma unroll
      for (int u = 0; u < 4; ++u) {
        half2v p0 = {(_Float16)a0[u], (_Float16)b0[u]};
        *(half2v*)&VT[g][(dg + u) * KSTR + kk] = p0;
        half2v p1 = {(_Float16)a1[u], (_Float16)b1[u]};
        *(half2v*)&VT[g][(dg + 4 + u) * KSTR + kk] = p1;
      }
    }
    if (t2 < 128) kss2[g][t2] = ks_s[((size_t)(b * L_) + k0 + (t2 >> 1)) * S_ + (t2 & 1)];
    __syncthreads();
    f32x4 acc[4];
#pragma unroll
    for (int nf = 0; nf < 4; ++nf) {
      f32x4 a = (f32x4){0.f, 0.f, 0.f, 0.f};
#pragma unroll
      for (int kb = 0; kb < 2; ++kb) {
        half8 kf = *(const half8*)&Ks[g][(nf * 16 + l16) * KSTR + kb * 32 + quad * 8];
        a = __builtin_amdgcn_mfma_f32_16x16x32_f16(qA[kb], kf, a, 0, 0, 0);
      }
      acc[nf] = a;
    }
#pragma unroll
    for (int nf = 0; nf < 4; ++nf) {
      float kx = kss2[g][(nf * 16 + l16) * 2 + 0];
      float ky = kss2[g][(nf * 16 + l16) * 2 + 1];
#pragma unroll
      for (int r = 0; r < 4; ++r) {
        float dx = qx[r] - kx, dy = qy[r] - ky;
        float dist = FAST_SQRT(fmaf(dx, dx, dy * dy));
        float tt = dist * FLSCALE;
        int ii = (int)tt;
        float fr = tt - (float)ii;
        f32x2 lh = LUT2s[ii];
        float p = __expf(acc[nf][r] + fmaf(fr, lh.y - lh.x, lh.x));
        acc[nf][r] = p;
      }
    }
#pragma unroll
    for (int r = 0; r < 4; ++r)
      l_r[r] += (acc[0][r] + acc[1][r]) + (acc[2][r] + acc[3][r]);
#pragma unroll
    for (int nf = 0; nf < 4; ++nf)
#pragma unroll
      for (int r = 0; r < 4; ++r)
        Pf[w][(quad * 4 + r) * PH + nf * 16 + l16] = (_Float16)acc[nf][r];
#pragma unroll
    for (int kb = 0; kb < 2; ++kb) {
      half8 pa = *(const half8*)&Pf[w][l16 * PH + kb * 32 + quad * 8];
#pragma unroll
      for (int df = 0; df < 4; ++df) {
        half8 vf = *(const half8*)&VT[g][(df * 16 + l16) * KSTR + kb * 32 + quad * 8];
        oc[df] = __builtin_amdgcn_mfma_f32_16x16x32_f16(pa, vf, oc[df], 0, 0, 0);
      }
    }
  }
  __syncthreads();
  float lred[4];
#pragma unroll
  for (int r = 0; r < 4; ++r) {
    float s = l_r[r];
    s += __shfl_xor(s, 1); s += __shfl_xor(s, 2);
    s += __shfl_xor(s, 4); s += __shfl_xor(s, 8);
    lred[r] = s;
  }
  if (g == 1) {
#pragma unroll
    for (int df = 0; df < 4; ++df)
#pragma unroll
      for (int r = 0; r < 4; ++r)
        comb[qw][quad * 4 + r][df * 16 + l16] = oc[df][r];
    if (l16 == 0) {
#pragma unroll
      for (int r = 0; r < 4; ++r) combl[qw][quad * 4 + r] = lred[r];
    }
  }
  __syncthreads();
  if (g == 0) {
    float inv_l[4];
#pragma unroll
    for (int r = 0; r < 4; ++r)
      inv_l[r] = 1.f / (lred[r] + combl[qw][quad * 4 + r]);
#pragma unroll
    for (int df = 0; df < 4; ++df)
#pragma unroll
      for (int r = 0; r < 4; ++r) {
        int qrow = q0 + qw * 16 + quad * 4 + r;
        float v = oc[df][r] + combl[qw][quad * 4 + r] * 0.f + comb[qw][quad * 4 + r][df * 16 + l16];
        out[(((size_t)(b * L_ + qrow)) * H_ + h) * D_ + df * 16 + l16] = v * inv_l[r];
      }
  }
}

extern "C" void kernel_launch(void* const* d_in, const int* in_sizes, int n_in,
                              void* d_out, int out_size, void* d_ws, size_t ws_size,
                              hipStream_t stream) {
  const float* qs = (const float*)d_in[0];
  const float* ks = (const float*)d_in[1];
  const float* vs = (const float*)d_in[2];
  const float* qs_s = (const float*)d_in[3];
  const float* ks_s = (const float*)d_in[4];
  const float* ap = (const float*)d_in[5];
  const float* bp = (const float*)d_in[6];
  const float* cp = (const float*)d_in[7];
  float* out = (float*)d_out;

  if (ws_size >= (size_t)WS_NEED) {
    _Float16* wsh = (_Float16*)d_ws;
    tisa_preproc<<<dim3(512), dim3(512), 0, stream>>>(qs, ks, vs, ks_s, wsh);
    tisa_attn_main<<<dim3(512), dim3(512), 0, stream>>>(qs_s, ap, bp, cp, wsh, out);
  } else {
    tisa_attn_fallback<<<dim3(512), dim3(512), 0, stream>>>(qs, ks, vs, qs_s, ks_s, ap, bp, cp, out);
  }
}

// Round 11
// 122.300 us; speedup vs baseline: 2.9207x; 1.0489x over previous
//
#include <hip/hip_runtime.h>
#include <cmath>

typedef _Float16 half8 __attribute__((ext_vector_type(8)));
typedef _Float16 half4 __attribute__((ext_vector_type(4)));
typedef _Float16 half2v __attribute__((ext_vector_type(2)));
typedef __fp16 fp16x2 __attribute__((ext_vector_type(2)));   // cvt_pkrtz return type
typedef float f32x4 __attribute__((ext_vector_type(4)));
typedef float f32x2 __attribute__((ext_vector_type(2)));

#define B_ 2
#define L_ 2048
#define H_ 8
#define D_ 64
#define S_ 2
#define F_ 5
#define LUTN 2048
#define LSCALE 1448.1547f          // LUTN / sqrt(2)
#define LOG2E 1.44269504f
#define QSC (0.125f * LOG2E)       // folded into Q at preprocess

// ws layout: Q tiles (64x64 f16, swizzled), K tiles (32x64 f16, swizzled),
// VT tiles (superrow-swizzled f16, KEY-PERMUTED for register-resident P),
// then pre-scaled ks_s coords (f32).
#define QOFF 0            // halfs
#define KOFF 2097152      // halfs
#define VOFF 4194304      // halfs
#define SOFFH 6291456     // halfs -> (float*)(wsh + SOFFH)
#define WS_NEED 12615680  // bytes

// main-kernel LDS arena (bytes): double-buffered K/V tiles + LUT (R7 config:
// 46.3 us, VGPR 64; grid 512 = 2 blocks/CU — single-buffer 4-block variant
// regressed because the grid caps residency at 2 blocks/CU anyway, R10).
#define OFF_K0 0
#define OFF_K1 16384
#define OFF_V0 32768
#define OFF_V1 49152
#define OFF_LUT 65536      // 2049 x 4 (+pad)
#define ARENA_SZ 73744
#define SLOTF (16 * 68 + 16)   // combine slot: O[16][68] f32 + l[16]

#define GLOBAL_LOAD_LDS16(g, l)                                                  \
  __builtin_amdgcn_global_load_lds((const __attribute__((address_space(1))) void*)(g), \
                                   (__attribute__((address_space(3))) void*)(l), 16, 0, 0)

// raw v_sqrt_f32 (1 ULP) — result only feeds a 2048-bin LUT quantizer.
#define FAST_SQRT(x) __builtin_amdgcn_sqrtf(x)

// ---------------- preprocessing: f32 -> f16 swizzled tiles in ws ----------------
// FUNCTION-SPLIT grid 1024 x 512 thr (preproc was grid-limited at 2 blocks/CU):
// blocks [0,512): Q chunks + K tiles + coords for (xcd,u,bh);
// blocks [512,1024): V register-transpose + key'-gather for the same (xcd,u,bh).
// -> 4 blocks/CU, 32 waves/CU, and each block has fewer dependent load phases.
#define VTS 68   // VT row stride in halfs (34 dwords; odd dword stride -> spread)
__global__ __launch_bounds__(512, 8)
void tisa_preproc(const float* __restrict__ qs, const float* __restrict__ ks,
                  const float* __restrict__ vs, const float* __restrict__ ks_s,
                  _Float16* __restrict__ wsh) {
  __shared__ _Float16 VT[64 * VTS];   // [d 64][key 64 (+4 pad)] (V blocks only)
  const int t = threadIdx.x;
  const int bid0 = blockIdx.x;
  const int bid = bid0 & 511;
  const int xcd = bid & 7, slot = bid >> 3;
  const int u = slot & 31;
  const int bh = xcd * 2 + (slot >> 5);
  const size_t base = ((size_t)(bh >> 3) * L_ + (size_t)u * 64) * (H_ * D_) + (size_t)(bh & 7) * D_;

  if (bid0 < 512) {
    // ---- Q: 512 chunks of 8 f32 -> 8 f16, swizzled chunk c^(row&7), scaled by QSC ----
    {
      int row = t >> 3, c = t & 7;
      const float* src = qs + base + (size_t)row * 512 + c * 8;
      f32x4 x0 = ((const f32x4*)src)[0], x1 = ((const f32x4*)src)[1];
      half8 hh;
#pragma unroll
      for (int k = 0; k < 4; ++k) { hh[k] = (_Float16)(x0[k] * QSC); hh[k + 4] = (_Float16)(x1[k] * QSC); }
      *(half8*)&wsh[QOFF + ((size_t)bh * 32 + u) * 4096 + row * 64 + (c ^ (row & 7)) * 8] = hh;
    }
    // ---- K: two 32-row tiles, same chunk swizzle ----
    {
      int tile = t >> 8, row = (t >> 3) & 31, c = t & 7;
      const float* src = ks + base + (size_t)(tile * 32 + row) * 512 + c * 8;
      f32x4 x0 = ((const f32x4*)src)[0], x1 = ((const f32x4*)src)[1];
      half8 hh;
#pragma unroll
      for (int k = 0; k < 4; ++k) { hh[k] = (_Float16)x0[k]; hh[k + 4] = (_Float16)x1[k]; }
      *(half8*)&wsh[KOFF + ((size_t)bh * 64 + u * 2 + tile) * 2048 + row * 64 + (c ^ (row & 7)) * 8] = hh;
    }
    // ---- scaled ks_s coords (h==0 blocks only; 64 keys = 128 floats) ----
    if ((bh & 7) == 0 && t < 32) {
      const int b = bh >> 3;
      const float* src = ks_s + ((size_t)b * L_ + u * 64) * 2 + t * 4;
      float* dst = (float*)(wsh + SOFFH) + ((size_t)b * L_ + u * 64) * 2 + t * 4;
      f32x4 x = *(const f32x4*)src;
      x *= LSCALE;
      *(f32x4*)dst = x;
    }
  } else {
    // ---- V: register transpose -> VT[d][key] (threads 0..255: 2 keys x 8 d) ----
    if (t < 256) {
      int kk = (t & 31) * 2, dg = (t >> 5) * 8;
      const float* s0 = vs + base + (size_t)kk * 512 + dg;
      const float* s1 = s0 + 512;
      f32x4 a0 = ((const f32x4*)s0)[0], a1 = ((const f32x4*)s0)[1];
      f32x4 b0 = ((const f32x4*)s1)[0], b1 = ((const f32x4*)s1)[1];
#pragma unroll
      for (int v = 0; v < 4; ++v) {
        half2v p0 = {(_Float16)a0[v], (_Float16)b0[v]};
        *(half2v*)&VT[(dg + v) * VTS + kk] = p0;
        half2v p1 = {(_Float16)a1[v], (_Float16)b1[v]};
        *(half2v*)&VT[(dg + 4 + v) * VTS + kk] = p1;
      }
    }
    __syncthreads();
    // ---- gather key'-ordered half8 from VT rows (2x contiguous b64), write ws ----
    //      key' = quad*8 + nf*4 + r  <=>  orig = nf*16 + quad*4 + r
    //      superrow s holds d=2s,2s+1; slot c' = (d&1)*4 + (key'>>3), stored c'^(s&7)
    {
      int tile = t >> 8, s = (t >> 3) & 31, cp2 = t & 7;
      int d = 2 * s + (cp2 >> 2), qp = cp2 & 3;
      half4 lo = *(const half4*)&VT[d * VTS + tile * 32 + qp * 4];        // nf=0
      half4 hi = *(const half4*)&VT[d * VTS + tile * 32 + 16 + qp * 4];   // nf=1
      half8 hh;
#pragma unroll
      for (int j = 0; j < 4; ++j) { hh[j] = lo[j]; hh[j + 4] = hi[j]; }
      *(half8*)&wsh[VOFF + ((size_t)bh * 64 + u * 2 + tile) * 2048 + s * 64 + (cp2 ^ (s & 7)) * 8] = hh;
    }
  }
}

// ---------------- main kernel: 512 thr = 8 waves = 4 K-quarters x 2 q-halves ---------
// R7 verbatim (46.3 us, VGPR 64): N_rep=2 — each wave owns TWO q-slices; kf/vf
// fragments are read from LDS ONCE and reused for both slices' MFMAs; K/V
// double-buffered with prefetch-before-compute.
__global__ __launch_bounds__(512, 4)
void tisa_attn_main(const float* __restrict__ qs_s, const float* __restrict__ ap,
                    const float* __restrict__ bp, const float* __restrict__ cp,
                    const _Float16* __restrict__ wsh, float* __restrict__ out) {
  __shared__ __align__(16) char arena[ARENA_SZ];
  float* LUT = (float*)(arena + OFF_LUT);

  const int t = threadIdx.x;
  const int lane = t & 63;
  const int w = t >> 6;       // 0..7
  const int g = w >> 1;       // K-quarter 0..3
  const int qh = w & 1;       // q-half 0..1 (owns q-slices 2qh, 2qh+1)
  const int tg = t & 127;     // index within group (2 waves)
  const int quad = lane >> 4;
  const int l16 = lane & 15;

  // XCD swizzle: each XCD gets a contiguous bh-pair -> K/V stays L2-resident.
  const int bid = blockIdx.x;
  const int xcd = bid & 7, slot = bid >> 3;
  const int qt = slot & 31;
  const int bh = xcd * 2 + (slot >> 5);
  const int h = bh & 7;
  const int b = bh >> 3;
  const int q0 = qt * 64;

  // ---- LUT (nearest-neighbor, midpoint-sampled): ((bias-8)*log2e) at d=(i+0.5)/LSCALE ----
  {
    float af[F_], nb[F_], cf[F_];
#pragma unroll
    for (int f = 0; f < F_; ++f) {
      af[f] = ap[h * F_ + f];
      nb[f] = -fabsf(bp[h * F_ + f]);
      cf[f] = cp[h * F_ + f];
    }
    for (int i = t; i <= LUTN; i += 512) {
      float d = ((float)i + 0.5f) * (1.0f / LSCALE);
      float s = 0.f;
#pragma unroll
      for (int f = 0; f < F_; ++f) {
        float e = d - cf[f];
        s += af[f] * __expf(nb[f] * (e * e));
      }
      LUT[i] = (s - 8.0f) * LOG2E;
    }
  }

  // q coords for this lane's two S^T columns (q = (2qh+s)*16 + l16), pre-scaled
  float qx[2], qy[2];
#pragma unroll
  for (int s = 0; s < 2; ++s) {
    qx[s] = qs_s[((size_t)b * L_ + q0 + (qh * 2 + s) * 16 + l16) * 2 + 0] * LSCALE;
    qy[s] = qs_s[((size_t)b * L_ + q0 + (qh * 2 + s) * 16 + l16) * 2 + 1] * LSCALE;
  }

  const _Float16* Qt = wsh + QOFF + ((size_t)bh * 32 + qt) * 4096;
  const _Float16* Kbh = wsh + KOFF + (size_t)bh * 64 * 2048;
  const _Float16* Vbh = wsh + VOFF + (size_t)bh * 64 * 2048;
  const float* wsS = (const float*)(wsh + SOFFH);

  // staging: group = 2 waves = 128 thr; K tile (4KB) = 2 rounds of 128x16B
  const _Float16* ksrc = Kbh + (size_t)(g * 16) * 2048 + tg * 8;
  const _Float16* vsrc = Vbh + (size_t)(g * 16) * 2048 + tg * 8;
  char* kdst = arena + OFF_K0 + g * 4096 + qh * 1024;   // wave-uniform
  char* vdst = arena + OFF_V0 + g * 4096 + qh * 1024;
  // per-lane k-coord base: keys (g*512 + it*32 + nf*16 + quad*4 + r), 2 floats each
  const float* sbase = wsS + ((size_t)b * L_ + g * 512 + quad * 4) * 2;

  // ---- prologue: Q tile (8 KB) -> K1 region (all 8 waves); K/V tile 0 -> buf0 ----
  GLOBAL_LOAD_LDS16(Qt + w * 512 + lane * 8, arena + OFF_K1 + w * 1024);
  GLOBAL_LOAD_LDS16(ksrc, kdst);
  GLOBAL_LOAD_LDS16(ksrc + 1024, kdst + 2048);
  GLOBAL_LOAD_LDS16(vsrc, vdst);
  GLOBAL_LOAD_LDS16(vsrc + 1024, vdst + 2048);
  ksrc += 2048; vsrc += 2048;
  __syncthreads();  // Q + tile0 landed (barrier drains vmcnt), LUT built

  half8 qA[2][2];   // [slice][kb]
#pragma unroll
  for (int s = 0; s < 2; ++s)
#pragma unroll
    for (int kb = 0; kb < 2; ++kb)
      qA[s][kb] = *(const half8*)(arena + OFF_K1 + ((qh * 2 + s) * 16 + l16) * 128 +
                                  ((kb * 4 + quad) ^ (l16 & 7)) * 16);
  __syncthreads();  // all qA reads done before iter-0 prefetch overwrites K1

  f32x4 oc[2][4];
#pragma unroll
  for (int s = 0; s < 2; ++s)
#pragma unroll
    for (int df = 0; df < 4; ++df) oc[s][df] = (f32x4){0.f, 0.f, 0.f, 0.f};
  f32x4 lsacc[2];
  lsacc[0] = (f32x4){0.f, 0.f, 0.f, 0.f};
  lsacc[1] = (f32x4){0.f, 0.f, 0.f, 0.f};
  half8 onesv;
#pragma unroll
  for (int j = 0; j < 8; ++j) onesv[j] = (_Float16)1.0f;

  int cur16 = 0;
  for (int it = 0; it < 16; ++it) {
    const int nxt16 = cur16 ^ 16384;
    // ---- prefetch tile it+1; barrier's vmcnt drain lands after compute phase
    if (it < 15) {
      GLOBAL_LOAD_LDS16(ksrc, kdst + nxt16);
      GLOBAL_LOAD_LDS16(ksrc + 1024, kdst + nxt16 + 2048);
      GLOBAL_LOAD_LDS16(vsrc, vdst + nxt16);
      GLOBAL_LOAD_LDS16(vsrc + 1024, vdst + nxt16 + 2048);
      ksrc += 2048; vsrc += 2048;
    }

    // ---- key coords (shared by both slices) ----
    const float* sit = sbase + it * 64;
    f32x4 cA = *(const f32x4*)(sit);          // nf=0: keys quad*4+0,1
    f32x4 cB = *(const f32x4*)(sit + 4);      // nf=0: keys quad*4+2,3
    f32x4 cC = *(const f32x4*)(sit + 32);     // nf=1
    f32x4 cD = *(const f32x4*)(sit + 36);
    float kx[8] = {cA.x, cA.z, cB.x, cB.z, cC.x, cC.z, cD.x, cD.z};
    float ky[8] = {cA.y, cA.w, cB.y, cB.w, cC.y, cC.w, cD.y, cD.w};

    // ---- S^T = K·Q^T: kf read ONCE, 8 MFMA (2 slices x 2 nf x 2 kb) ----
    half8 kf[2][2];
#pragma unroll
    for (int nf = 0; nf < 2; ++nf)
#pragma unroll
      for (int kb = 0; kb < 2; ++kb)
        kf[nf][kb] = *(const half8*)(arena + OFF_K0 + cur16 + g * 4096 +
                                     (nf * 16 + l16) * 128 + ((kb * 4 + quad) ^ (l16 & 7)) * 16);
    f32x4 acc[2][2];
#pragma unroll
    for (int s = 0; s < 2; ++s)
#pragma unroll
      for (int nf = 0; nf < 2; ++nf) {
        f32x4 a = (f32x4){0.f, 0.f, 0.f, 0.f};
        a = __builtin_amdgcn_mfma_f32_16x16x32_f16(kf[nf][0], qA[s][0], a, 0, 0, 0);
        a = __builtin_amdgcn_mfma_f32_16x16x32_f16(kf[nf][1], qA[s][1], a, 0, 0, 0);
        acc[s][nf] = a;  // P[q][key'=quad*8+nf*4+r]
      }

    // ---- scores: dist -> LDS-LUT gather -> exp2; P packed in registers ----
    half8 pw[2];
#pragma unroll
    for (int s = 0; s < 2; ++s) {
      float parr[8];
#pragma unroll
      for (int j = 0; j < 8; ++j) {
        float dx = qx[s] - kx[j], dy = qy[s] - ky[j];
        float tt = FAST_SQRT(fmaf(dx, dx, dy * dy));   // = dist * LSCALE
        parr[j] = __builtin_amdgcn_exp2f(acc[s][j >> 2][j & 3] + LUT[(int)tt]);
      }
      union { half8 h8; fp16x2 h2[4]; } pu;
#pragma unroll
      for (int k = 0; k < 4; ++k)
        pu.h2[k] = __builtin_amdgcn_cvt_pkrtz(parr[2 * k], parr[2 * k + 1]);
      pw[s] = pu.h8;
    }

    // ---- PV + row-sum; vf read ONCE, used by both slices ----
    lsacc[0] = __builtin_amdgcn_mfma_f32_16x16x32_f16(pw[0], onesv, lsacc[0], 0, 0, 0);
    lsacc[1] = __builtin_amdgcn_mfma_f32_16x16x32_f16(pw[1], onesv, lsacc[1], 0, 0, 0);
#pragma unroll
    for (int df = 0; df < 4; ++df) {
      half8 vf = *(const half8*)(arena + OFF_V0 + cur16 + g * 4096 + (l16 >> 1) * 128 + df * 1024 +
                                 ((((l16 & 1) * 4 + quad) ^ ((l16 >> 1) & 7)) * 16));
      oc[0][df] = __builtin_amdgcn_mfma_f32_16x16x32_f16(pw[0], vf, oc[0][df], 0, 0, 0);
      oc[1][df] = __builtin_amdgcn_mfma_f32_16x16x32_f16(pw[1], vf, oc[1][df], 0, 0, 0);
    }

    __syncthreads();  // buf[cur] reads done; prefetched tile landed & visible
    cur16 = nxt16;
  }

  // ---- combine 4 K-quarters via LDS tree (row sums already reduced by ones-MFMA) ----
  float lred[2][4];
#pragma unroll
  for (int s = 0; s < 2; ++s)
#pragma unroll
    for (int r = 0; r < 4; ++r) lred[s][r] = lsacc[s][r];
  __syncthreads();  // arena reusable
  float* slots = (float*)arena;
  if (g >= 2) {
#pragma unroll
    for (int s = 0; s < 2; ++s) {
      float* sl = slots + ((g - 2) * 4 + qh * 2 + s) * SLOTF;
#pragma unroll
      for (int df = 0; df < 4; ++df)
#pragma unroll
        for (int r = 0; r < 4; ++r)
          sl[(quad * 4 + r) * 68 + df * 16 + l16] = oc[s][df][r];
      if (l16 == 0) {
#pragma unroll
        for (int r = 0; r < 4; ++r) sl[16 * 68 + quad * 4 + r] = lred[s][r];
      }
    }
  }
  __syncthreads();
  if (g < 2) {
#pragma unroll
    for (int s = 0; s < 2; ++s) {
      float* sl = slots + (g * 4 + qh * 2 + s) * SLOTF;   // g0<-slot(g2), g1<-slot(g3)
#pragma unroll
      for (int df = 0; df < 4; ++df)
#pragma unroll
        for (int r = 0; r < 4; ++r)
          oc[s][df][r] += sl[(quad * 4 + r) * 68 + df * 16 + l16];
#pragma unroll
      for (int r = 0; r < 4; ++r) lred[s][r] += sl[16 * 68 + quad * 4 + r];
    }
  }
  if (g == 1) {  // write combined back into same slot (same-wave, in-order)
#pragma unroll
    for (int s = 0; s < 2; ++s) {
      float* sl = slots + (4 + qh * 2 + s) * SLOTF;
#pragma unroll
      for (int df = 0; df < 4; ++df)
#pragma unroll
        for (int r = 0; r < 4; ++r)
          sl[(quad * 4 + r) * 68 + df * 16 + l16] = oc[s][df][r];
      if (l16 == 0) {
#pragma unroll
        for (int r = 0; r < 4; ++r) sl[16 * 68 + quad * 4 + r] = lred[s][r];
      }
    }
  }
  __syncthreads();
  if (g == 0) {
#pragma unroll
    for (int s = 0; s < 2; ++s) {
      float* sl = slots + (4 + qh * 2 + s) * SLOTF;
      float inv_l[4];
#pragma unroll
      for (int r = 0; r < 4; ++r)
        inv_l[r] = 1.f / (lred[s][r] + sl[16 * 68 + quad * 4 + r]);
#pragma unroll
      for (int df = 0; df < 4; ++df)
#pragma unroll
        for (int r = 0; r < 4; ++r) {
          int qrow = q0 + (qh * 2 + s) * 16 + quad * 4 + r;
          float v = oc[s][df][r] + sl[(quad * 4 + r) * 68 + df * 16 + l16];
          out[((size_t)(b * L_ + qrow)) * (H_ * D_) + h * D_ + df * 16 + l16] = v * inv_l[r];
        }
    }
  }
}

// ---------------- fallback (R3 kernel) if ws too small ----------------
#define KSTR 72
#define PH 72
#define FLUTN 512
#define FLSCALE 362.03867f
__global__ __launch_bounds__(512, 4)
void tisa_attn_fallback(const float* __restrict__ qs, const float* __restrict__ ks,
                        const float* __restrict__ vs, const float* __restrict__ qs_s,
                        const float* __restrict__ ks_s, const float* __restrict__ ap,
                        const float* __restrict__ bp, const float* __restrict__ cp,
                        float* __restrict__ out) {
  __shared__ _Float16 Ks[2][64 * KSTR];
  __shared__ _Float16 VT[2][D_ * KSTR];
  __shared__ _Float16 Pf[8][16 * PH];
  __shared__ float kss2[2][64 * 2];
  __shared__ f32x2 LUT2s[FLUTN + 1];
  __shared__ float comb[4][16][64];
  __shared__ float combl[4][16];

  const int t = threadIdx.x;
  const int lane = t & 63;
  const int w = t >> 6;
  const int g = w >> 2;
  const int qw = w & 3;
  const int t2 = t & 255;
  const int quad = lane >> 4;
  const int l16 = lane & 15;
  const int qt = blockIdx.x & 31;
  const int bh = blockIdx.x >> 5;
  const int h = bh & 7;
  const int b = bh >> 3;
  const int q0 = qt * 64;

  float af[F_], nb[F_], cf[F_];
#pragma unroll
  for (int f = 0; f < F_; ++f) {
    af[f] = ap[h * F_ + f];
    nb[f] = -fabsf(bp[h * F_ + f]);
    cf[f] = cp[h * F_ + f];
  }
  for (int i = t; i <= FLUTN; i += 512) {
    float d0 = (float)i * (1.0f / FLSCALE), d1 = (float)(i + 1) * (1.0f / FLSCALE);
    float s0 = 0.f, s1 = 0.f;
#pragma unroll
    for (int f = 0; f < F_; ++f) {
      float e0 = d0 - cf[f], e1 = d1 - cf[f];
      s0 += af[f] * __expf(nb[f] * (e0 * e0));
      s1 += af[f] * __expf(nb[f] * (e1 * e1));
    }
    LUT2s[i] = (f32x2){s0 - 8.0f, s1 - 8.0f};
  }
  float qx[4], qy[4];
#pragma unroll
  for (int r = 0; r < 4; ++r) {
    int qrow = q0 + qw * 16 + quad * 4 + r;
    qx[r] = qs_s[(b * L_ + qrow) * S_ + 0];
    qy[r] = qs_s[(b * L_ + qrow) * S_ + 1];
  }
  if (t < 256) {
    const int row = t >> 2, dc = (t & 3) * 16;
    const float* src = qs + (((size_t)(b * L_ + q0 + row)) * H_ + h) * D_ + dc;
    const f32x4* s4 = (const f32x4*)src;
    f32x4 v0 = s4[0], v1 = s4[1], v2 = s4[2], v3 = s4[3];
    half8 w0, w1;
#pragma unroll
    for (int u = 0; u < 4; ++u) {
      w0[u] = (_Float16)(v0[u] * 0.125f); w0[u + 4] = (_Float16)(v1[u] * 0.125f);
      w1[u] = (_Float16)(v2[u] * 0.125f); w1[u + 4] = (_Float16)(v3[u] * 0.125f);
    }
    *(half8*)&Ks[0][row * KSTR + dc] = w0;
    *(half8*)&Ks[0][row * KSTR + dc + 8] = w1;
  }
  __syncthreads();
  half8 qA[2];
#pragma unroll
  for (int kb = 0; kb < 2; ++kb)
    qA[kb] = *(const half8*)&Ks[0][(qw * 16 + l16) * KSTR + kb * 32 + quad * 8];
  f32x4 oc[4];
#pragma unroll
  for (int df = 0; df < 4; ++df) oc[df] = (f32x4){0.f, 0.f, 0.f, 0.f};
  float l_r[4] = {0.f, 0.f, 0.f, 0.f};

  for (int it = 0; it < 16; ++it) {
    const int k0 = (g * 16 + it) * 64;
    __syncthreads();
    {
      const int row = t2 >> 2, dc = (t2 & 3) * 16;
      const float* src = ks + (((size_t)(b * L_ + k0 + row)) * H_ + h) * D_ + dc;
      const f32x4* s4 = (const f32x4*)src;
      f32x4 v0 = s4[0], v1 = s4[1], v2 = s4[2], v3 = s4[3];
      half8 w0, w1;
#pragma unroll
      for (int u = 0; u < 4; ++u) {
        w0[u] = (_Float16)v0[u]; w0[u + 4] = (_Float16)v1[u];
        w1[u] = (_Float16)v2[u]; w1[u + 4] = (_Float16)v3[u];
      }
      *(half8*)&Ks[g][row * KSTR + dc] = w0;
      *(half8*)&Ks[g][row * KSTR + dc + 8] = w1;
    }
    {
      const int kk = (t2 & 31) * 2, dg = (t2 >> 5) * 8;
      const float* s0 = vs + (((size_t)(b * L_ + k0 + kk)) * H_ + h) * D_ + dg;
      const float* s1 = s0 + H_ * D_;
      f32x4 a0 = ((const f32x4*)s0)[0], a1 = ((const f32x4*)s0)[1];
      f32x4 b0 = ((const f32x4*)s1)[0], b1 = ((const f32x4*)s1)[1];
#pragma unroll
      for (int u = 0; u < 4; ++u) {
        half2v p0 = {(_Float16)a0[u], (_Float16)b0[u]};
        *(half2v*)&VT[g][(dg + u) * KSTR + kk] = p0;
        half2v p1 = {(_Float16)a1[u], (_Float16)b1[u]};
        *(half2v*)&VT[g][(dg + 4 + u) * KSTR + kk] = p1;
      }
    }
    if (t2 < 128) kss2[g][t2] = ks_s[((size_t)(b * L_) + k0 + (t2 >> 1)) * S_ + (t2 & 1)];
    __syncthreads();
    f32x4 acc[4];
#pragma unroll
    for (int nf = 0; nf < 4; ++nf) {
      f32x4 a = (f32x4){0.f, 0.f, 0.f, 0.f};
#pragma unroll
      for (int kb = 0; kb < 2; ++kb) {
        half8 kf = *(const half8*)&Ks[g][(nf * 16 + l16) * KSTR + kb * 32 + quad * 8];
        a = __builtin_amdgcn_mfma_f32_16x16x32_f16(qA[kb], kf, a, 0, 0, 0);
      }
      acc[nf] = a;
    }
#pragma unroll
    for (int nf = 0; nf < 4; ++nf) {
      float kx = kss2[g][(nf * 16 + l16) * 2 + 0];
      float ky = kss2[g][(nf * 16 + l16) * 2 + 1];
#pragma unroll
      for (int r = 0; r < 4; ++r) {
        float dx = qx[r] - kx, dy = qy[r] - ky;
        float dist = FAST_SQRT(fmaf(dx, dx, dy * dy));
        float tt = dist * FLSCALE;
        int ii = (int)tt;
        float fr = tt - (float)ii;
        f32x2 lh = LUT2s[ii];
        float p = __expf(acc[nf][r] + fmaf(fr, lh.y - lh.x, lh.x));
        acc[nf][r] = p;
      }
    }
#pragma unroll
    for (int r = 0; r < 4; ++r)
      l_r[r] += (acc[0][r] + acc[1][r]) + (acc[2][r] + acc[3][r]);
#pragma unroll
    for (int nf = 0; nf < 4; ++nf)
#pragma unroll
      for (int r = 0; r < 4; ++r)
        Pf[w][(quad * 4 + r) * PH + nf * 16 + l16] = (_Float16)acc[nf][r];
#pragma unroll
    for (int kb = 0; kb < 2; ++kb) {
      half8 pa = *(const half8*)&Pf[w][l16 * PH + kb * 32 + quad * 8];
#pragma unroll
      for (int df = 0; df < 4; ++df) {
        half8 vf = *(const half8*)&VT[g][(df * 16 + l16) * KSTR + kb * 32 + quad * 8];
        oc[df] = __builtin_amdgcn_mfma_f32_16x16x32_f16(pa, vf, oc[df], 0, 0, 0);
      }
    }
  }
  __syncthreads();
  float lred[4];
#pragma unroll
  for (int r = 0; r < 4; ++r) {
    float s = l_r[r];
    s += __shfl_xor(s, 1); s += __shfl_xor(s, 2);
    s += __shfl_xor(s, 4); s += __shfl_xor(s, 8);
    lred[r] = s;
  }
  if (g == 1) {
#pragma unroll
    for (int df = 0; df < 4; ++df)
#pragma unroll
      for (int r = 0; r < 4; ++r)
        comb[qw][quad * 4 + r][df * 16 + l16] = oc[df][r];
    if (l16 == 0) {
#pragma unroll
      for (int r = 0; r < 4; ++r) combl[qw][quad * 4 + r] = lred[r];
    }
  }
  __syncthreads();
  if (g == 0) {
    float inv_l[4];
#pragma unroll
    for (int r = 0; r < 4; ++r)
      inv_l[r] = 1.f / (lred[r] + combl[qw][quad * 4 + r]);
#pragma unroll
    for (int df = 0; df < 4; ++df)
#pragma unroll
      for (int r = 0; r < 4; ++r) {
        int qrow = q0 + qw * 16 + quad * 4 + r;
        float v = oc[df][r] + combl[qw][quad * 4 + r] * 0.f + comb[qw][quad * 4 + r][df * 16 + l16];
        out[(((size_t)(b * L_ + qrow)) * H_ + h) * D_ + df * 16 + l16] = v * inv_l[r];
      }
  }
}

extern "C" void kernel_launch(void* const* d_in, const int* in_sizes, int n_in,
                              void* d_out, int out_size, void* d_ws, size_t ws_size,
                              hipStream_t stream) {
  const float* qs = (const float*)d_in[0];
  const float* ks = (const float*)d_in[1];
  const float* vs = (const float*)d_in[2];
  const float* qs_s = (const float*)d_in[3];
  const float* ks_s = (const float*)d_in[4];
  const float* ap = (const float*)d_in[5];
  const float* bp = (const float*)d_in[6];
  const float* cp = (const float*)d_in[7];
  float* out = (float*)d_out;

  if (ws_size >= (size_t)WS_NEED) {
    _Float16* wsh = (_Float16*)d_ws;
    tisa_preproc<<<dim3(1024), dim3(512), 0, stream>>>(qs, ks, vs, ks_s, wsh);
    tisa_attn_main<<<dim3(512), dim3(512), 0, stream>>>(qs_s, ap, bp, cp, wsh, out);
  } else {
    tisa_attn_fallback<<<dim3(512), dim3(512), 0, stream>>>(qs, ks, vs, qs_s, ks_s, ap, bp, cp, out);
  }
}